// Round 2
// baseline (9267.950 us; speedup 1.0000x reference)
//
#include <hip/hip_runtime.h>

// ---------------------------------------------------------------------------
// Two 2-layer LSTMs (H=1024) + 29-step autoregressive scan (state resets each
// step => scan needs only Wih matmuls). f16 MFMA 16x16x32, fp32 accumulate,
// gates fused in GEMM epilogue.
// Round 2: BK=32 (LDS 32KB -> 4-5 blocks/CU), v/a chains merged (M=4096),
// scan as ONE persistent kernel with device-scope atomic grid barrier.
// ---------------------------------------------------------------------------

#define B_    2048
#define OBS_  20
#define PRED_ 30
#define F_    16
#define H_    1024
#define GN_   4096   // 4*H

typedef _Float16 f16;
typedef _Float16 f16x8 __attribute__((ext_vector_type(8)));
typedef _Float16 f16x4 __attribute__((ext_vector_type(4)));
typedef float    f32x4 __attribute__((ext_vector_type(4)));

__device__ __forceinline__ float fast_sigmoid(float x) {
  return 1.0f / (1.0f + __expf(-x));
}
__device__ __forceinline__ float fast_tanh(float x) {
  float ax = fabsf(x);
  float e  = __expf(-2.0f * ax);
  float r  = (1.0f - e) / (1.0f + e);
  return copysignf(r, x);
}

// ---------------------------------------------------------------------------
// shared GEMM building blocks (BK=32, tile 128 rows x 32 j-cols, 4 waves 2x2)
// LDS tile [128][32] f16 = 8KB; 4 16B slots/row; swizzle slot ^= (row>>1)&3
// => ds_read_b128 is 2-way bank-aliased (free). Staged with global_load_lds
// (linear LDS dest, inverse-swizzled global source).
// ---------------------------------------------------------------------------
__device__ __forceinline__ void stageA(f16* dst, const f16* Asrc, int b0, int k0, int tid) {
#pragma unroll
  for (int cc = 0; cc < 2; ++cc) {
    int o  = cc * 4096 + tid * 16;
    int rr = o >> 6;
    int sp = (o >> 4) & 3;
    int sl = sp ^ ((rr >> 1) & 3);
    const f16* gp = Asrc + (size_t)(b0 + rr) * H_ + k0 + sl * 8;
    __builtin_amdgcn_global_load_lds(
        (const __attribute__((address_space(1))) void*)gp,
        (__attribute__((address_space(3))) void*)((char*)dst + o), 16, 0, 0);
  }
}
__device__ __forceinline__ void stageB(f16* dst, const f16* Wsrc, int j0, int k0, int tid) {
#pragma unroll
  for (int cc = 0; cc < 2; ++cc) {
    int o  = cc * 4096 + tid * 16;
    int rr = o >> 6;
    int sp = (o >> 4) & 3;
    int sl = sp ^ ((rr >> 1) & 3);
    int row = (rr >> 5) * H_ + j0 + (rr & 31);     // gate*1024 + j
    const f16* gp = Wsrc + (size_t)row * H_ + k0 + sl * 8;
    __builtin_amdgcn_global_load_lds(
        (const __attribute__((address_space(1))) void*)gp,
        (__attribute__((address_space(3))) void*)((char*)dst + o), 16, 0, 0);
  }
}

__device__ __forceinline__ void acc_init(f32x4 (&acc)[4][4], const float* bias, int jcol) {
#pragma unroll
  for (int g = 0; g < 4; ++g) {
    float bv = bias[g * H_ + jcol];
#pragma unroll
    for (int m = 0; m < 4; ++m) acc[m][g] = (f32x4){bv, bv, bv, bv};
  }
}

// K=16 input term, zero-padded to one K=32 MFMA slice
__device__ __forceinline__ void run_k16(f32x4 (&acc)[4][4], const f16* A16, const f16* W16,
    int b0, int j0, int wr, int wc, int lcol, int lkq)
{
  f16x8 za = {0, 0, 0, 0, 0, 0, 0, 0};
  f16x8 af[4], bf[4];
#pragma unroll
  for (int m = 0; m < 4; ++m) {
    if (lkq < 2) {
      int row = b0 + wr * 64 + m * 16 + lcol;
      af[m] = *(const f16x8*)(A16 + (size_t)row * 16 + lkq * 8);
    } else af[m] = za;
  }
#pragma unroll
  for (int g = 0; g < 4; ++g) {
    if (lkq < 2) {
      int row = g * H_ + j0 + wc * 16 + lcol;
      bf[g] = *(const f16x8*)(W16 + (size_t)row * 16 + lkq * 8);
    } else bf[g] = za;
  }
#pragma unroll
  for (int m = 0; m < 4; ++m)
#pragma unroll
    for (int g = 0; g < 4; ++g)
      acc[m][g] = __builtin_amdgcn_mfma_f32_16x16x32_f16(af[m], bf[g], acc[m][g], 0, 0, 0);
}

// main K loop; caller must have staged tile 0 into lA[0]/lB[0]
template<int NMAIN>
__device__ __forceinline__ void run_kloop(f32x4 (&acc)[4][4], f16 (*lA)[4096], f16 (*lB)[4096],
    const f16* A0, const f16* W0, const f16* A1, const f16* W1,
    int b0, int j0, int tid, int wr, int wc, int lcol, int lkq)
{
  const int NT = NMAIN * 32;
  __syncthreads();
  int cur = 0;
  for (int t = 0; t < NT; ++t) {
    if (t + 1 < NT) {
      int tn = t + 1;
      const f16* As = (NMAIN == 2 && tn >= 32) ? A1 : A0;
      const f16* Ws = (NMAIN == 2 && tn >= 32) ? W1 : W0;
      int k0 = (tn & 31) * 32;
      stageA(lA[cur ^ 1], As, b0, k0, tid);
      stageB(lB[cur ^ 1], Ws, j0, k0, tid);
    }
    f16x8 av[4], bw[4];
#pragma unroll
    for (int m = 0; m < 4; ++m) {
      int ar = wr * 64 + m * 16 + lcol;
      int sa = lkq ^ ((ar >> 1) & 3);
      av[m] = *(const f16x8*)&lA[cur][ar * 32 + sa * 8];
    }
#pragma unroll
    for (int g = 0; g < 4; ++g) {
      int br = g * 32 + wc * 16 + lcol;
      int sb = lkq ^ ((br >> 1) & 3);
      bw[g] = *(const f16x8*)&lB[cur][br * 32 + sb * 8];
    }
#pragma unroll
    for (int m = 0; m < 4; ++m)
#pragma unroll
      for (int g = 0; g < 4; ++g)
        acc[m][g] = __builtin_amdgcn_mfma_f32_16x16x32_f16(av[m], bw[g], acc[m][g], 0, 0, 0);
    __syncthreads();
    cur ^= 1;
  }
}

__device__ __forceinline__ void lstm_epi(f32x4 (&acc)[4][4], const float* cin, float* cout,
    f16* hout, int b0, int jcol, int wr, int lkq, bool hasc, bool writec)
{
#pragma unroll
  for (int m = 0; m < 4; ++m) {
    int brow0 = b0 + wr * 64 + m * 16 + lkq * 4;
#pragma unroll
    for (int r = 0; r < 4; ++r) {
      size_t bi = (size_t)(brow0 + r) * H_ + jcol;
      float gi = acc[m][0][r], gf = acc[m][1][r], gg = acc[m][2][r], go = acc[m][3][r];
      float cold = hasc ? cin[bi] : 0.0f;
      float cn = fast_sigmoid(gf) * cold + fast_sigmoid(gi) * fast_tanh(gg);
      float hv = fast_sigmoid(go) * fast_tanh(cn);
      if (writec) cout[bi] = cn;
      hout[bi] = (f16)hv;
    }
  }
}

// ---------------------------------------------------------------------------
// observation-phase fused LSTM step; v/a chains merged along batch (bm<16 = v)
// ---------------------------------------------------------------------------
struct StepArgs {
  const f16* A16;
  const f16* W16v; const f16* W16a;
  const f16* A0;  const f16* W0v; const f16* W0a;
  const f16* A1;  const f16* W1v; const f16* W1a;
  const float* bv; const float* ba;
  const float* cin; float* cout; f16* hout;
};

template<int K16, int NMAIN, int HASC, int WRITEC>
__global__ __launch_bounds__(256, 4)
void lstm_step(StepArgs p)
{
  __shared__ f16 lA[2][4096];
  __shared__ f16 lB[2][4096];
  const int tid = threadIdx.x, lane = tid & 63;
  const int wv = tid >> 6, wr = wv >> 1, wc = wv & 1;
  const int bm = blockIdx.x >> 5, bn = blockIdx.x & 31;
  const int b0 = bm * 128, j0 = bn * 32;
  const int ch = bm >> 4;
  const int lcol = lane & 15, lkq = lane >> 4;
  const int jcol = j0 + wc * 16 + lcol;

  const f16* W16 = ch ? p.W16a : p.W16v;
  const f16* W0  = ch ? p.W0a  : p.W0v;
  const f16* W1  = ch ? p.W1a  : p.W1v;
  const float* bias = ch ? p.ba : p.bv;

  if (NMAIN > 0) { stageA(lA[0], p.A0, b0, 0, tid); stageB(lB[0], W0, j0, 0, tid); }

  f32x4 acc[4][4];
  acc_init(acc, bias, jcol);
  if (K16) run_k16(acc, p.A16, W16, b0, j0, wr, wc, lcol, lkq);
  if (NMAIN > 0)
    run_kloop<NMAIN>(acc, lA, lB, p.A0, W0, p.A1, W1, b0, j0, tid, wr, wc, lcol, lkq);
  lstm_epi(acc, p.cin, p.cout, p.hout, b0, jcol, wr, lkq, HASC != 0, WRITEC != 0);
}

// ---------------------------------------------------------------------------
// device-scope grid barrier (512 resident blocks; 32KB LDS => >=4 blocks/CU)
// ---------------------------------------------------------------------------
__device__ __forceinline__ void grid_bar(unsigned* bar, unsigned target) {
  __syncthreads();
  if (threadIdx.x == 0) {
    __hip_atomic_fetch_add(bar, 1u, __ATOMIC_ACQ_REL, __HIP_MEMORY_SCOPE_AGENT);
    while (__hip_atomic_load(bar, __ATOMIC_ACQUIRE, __HIP_MEMORY_SCOPE_AGENT) < target) {
      __builtin_amdgcn_s_sleep(2);
    }
  }
  __syncthreads();
}

// ---------------------------------------------------------------------------
// persistent scan kernel: 29 iterations of {layer0(K16) | layer1(K=1024) |
// proj+update}, separated by grid barriers. Zero LSTM state each step.
// ---------------------------------------------------------------------------
struct ScanArgs {
  const f16 *Wih0, *Wih1;
  const float *b0g, *b1g;
  const float *Wl, *bl, *sv;
  f16 *a16; float *v_buf, *x_buf; float *out;
  f16 *h0, *h1;
  unsigned *bar;
};

__global__ __launch_bounds__(256, 4)
void scan_kernel(ScanArgs s)
{
  __shared__ f16 lA[2][4096];
  __shared__ f16 lB[2][4096];
  const int tid = threadIdx.x, lane = tid & 63;
  const int wv = tid >> 6, wr = wv >> 1, wc = wv & 1;
  const int bm = blockIdx.x >> 5, bn = blockIdx.x & 31;
  const int b0 = bm * 128, j0 = bn * 32;
  const int lcol = lane & 15, lkq = lane >> 4;
  const int jcol = j0 + wc * 16 + lcol;
  unsigned tgt = 0;

  for (int t = 1; t < PRED_; ++t) {
    // ---- phase A: layer0, K=16 only (zero state) ----
    {
      f32x4 acc[4][4];
      acc_init(acc, s.b0g, jcol);
      run_k16(acc, s.a16, s.Wih0, b0, j0, wr, wc, lcol, lkq);
      lstm_epi(acc, nullptr, nullptr, s.h0, b0, jcol, wr, lkq, false, false);
    }
    tgt += 512; grid_bar(s.bar, tgt);

    // ---- phase B: layer1, K=1024 ----
    {
      f32x4 acc[4][4];
      acc_init(acc, s.b1g, jcol);
      stageA(lA[0], s.h0, b0, 0, tid);
      stageB(lB[0], s.Wih1, j0, 0, tid);
      run_kloop<1>(acc, lA, lB, s.h0, s.Wih1, nullptr, nullptr, b0, j0, tid, wr, wc, lcol, lkq);
      lstm_epi(acc, nullptr, nullptr, s.h1, b0, jcol, wr, lkq, false, false);
    }
    tgt += 512; grid_bar(s.bar, tgt);

    // ---- phase C: proj + scan update (4 batch rows per block) ----
    {
      int d = tid >> 2, q = tid & 3;
      int row = blockIdx.x * 4 + (d >> 4), f = d & 15;
      const f16* hp = s.h1 + (size_t)row * H_ + q * 256;
      const float* wp = s.Wl + (size_t)f * H_ + q * 256;
      float a0 = 0, a1 = 0, a2 = 0, a3 = 0;
#pragma unroll 8
      for (int i = 0; i < 256; i += 8) {
        f16x8 h8 = *(const f16x8*)(hp + i);
        float4 w0 = *(const float4*)(wp + i);
        float4 w1 = *(const float4*)(wp + i + 4);
        a0 += (float)h8[0] * w0.x + (float)h8[4] * w1.x;
        a1 += (float)h8[1] * w0.y + (float)h8[5] * w1.y;
        a2 += (float)h8[2] * w0.z + (float)h8[6] * w1.z;
        a3 += (float)h8[3] * w0.w + (float)h8[7] * w1.w;
      }
      float acc = (a0 + a1) + (a2 + a3);
      acc += __shfl_down(acc, 1);
      acc += __shfl_down(acc, 2);
      if (q == 0) {
        float tv = fast_tanh(acc + s.bl[f]);
        int idx = row * F_ + f;
        float v = s.v_buf[idx] + s.sv[0] * tv;
        s.v_buf[idx] = v;
        float x = s.x_buf[idx] + v;
        s.x_buf[idx] = x;
        s.out[(size_t)t * B_ * F_ + idx] = x;
        s.a16[idx] = (f16)tv;
      }
    }
    if (t < PRED_ - 1) { tgt += 512; grid_bar(s.bar, tgt); }
  }
}

// ---------------------------------------------------------------------------
// projection heads for the observation phase (unchanged from round 1)
// ---------------------------------------------------------------------------
template<int MODE>
__global__ __launch_bounds__(256)
void proj_update(const f16* __restrict__ h1, const float* __restrict__ Wl,
                 const float* __restrict__ bl, const float* __restrict__ sv,
                 float* __restrict__ v_buf, float* __restrict__ x_buf,
                 float* __restrict__ out_t, f16* __restrict__ a16)
{
  __shared__ f16 lh[16 * 1024];
  const int b0r = blockIdx.x * 16;
  const int tid = threadIdx.x;
#pragma unroll
  for (int c = 0; c < 8; ++c) {
    int o = c * 256 + tid;
    *(f16x8*)&lh[o * 8] = *(const f16x8*)&h1[(size_t)b0r * 1024 + o * 8];
  }
  __syncthreads();
  const int br = tid >> 4;
  const int f  = tid & 15;
  float s0 = 0, s1 = 0, s2 = 0, s3 = 0;
  const float4* wp = (const float4*)(Wl + (size_t)f * 1024);
#pragma unroll 4
  for (int k8 = 0; k8 < 128; ++k8) {
    f16x8 hv = *(const f16x8*)&lh[br * 1024 + k8 * 8];
    float4 w0 = wp[k8 * 2], w1 = wp[k8 * 2 + 1];
    s0 += (float)hv[0] * w0.x + (float)hv[4] * w1.x;
    s1 += (float)hv[1] * w0.y + (float)hv[5] * w1.y;
    s2 += (float)hv[2] * w0.z + (float)hv[6] * w1.z;
    s3 += (float)hv[3] * w0.w + (float)hv[7] * w1.w;
  }
  float t = fast_tanh(bl[f] + ((s0 + s1) + (s2 + s3)));
  int idx = (b0r + br) * F_ + f;
  if (MODE == 0) {
    v_buf[idx] = sv[0] * t;
  } else {
    float v = v_buf[idx] + sv[0] * t;
    v_buf[idx] = v;
    float x = x_buf[idx] + v;
    x_buf[idx] = x;
    out_t[idx] = x;
    a16[idx] = (f16)t;
  }
}

// ---------------------------------------------------------------------------
// input prep: merged m16 [t][4096][16] (v rows 0-2047 = v_seq, a rows 2048+ =
// a_seq), yT (second output), x0
// ---------------------------------------------------------------------------
__global__ void prep_kernel(const float* __restrict__ x_in, const float* __restrict__ y,
                            const float* __restrict__ v_in, const float* __restrict__ sx,
                            float* __restrict__ out, float* __restrict__ x_buf,
                            f16* __restrict__ m16)
{
  const float s = sx[0];
  int gid = blockIdx.x * blockDim.x + threadIdx.x;
  int gs  = gridDim.x * blockDim.x;
  for (int i = gid; i < B_ * OBS_ * F_; i += gs) {
    int b = i / (OBS_ * F_);
    int rem = i - b * (OBS_ * F_);
    int t = rem >> 4;
    int f = rem & 15;
    float v = v_in[i];
    m16[((size_t)t * 4096 + b) * F_ + f] = (f16)v;
    if (t < OBS_ - 1)
      m16[((size_t)t * 4096 + 2048 + b) * F_ + f] = (f16)(v_in[i + F_] - v);
  }
  for (int i = gid; i < PRED_ * B_ * F_; i += gs) {
    int t = i / (B_ * F_);
    int rem = i - t * (B_ * F_);
    int b = rem >> 4;
    int f = rem & 15;
    out[PRED_ * B_ * F_ + i] = s * y[(b * PRED_ + t) * F_ + f];
  }
  for (int i = gid; i < B_ * F_; i += gs) {
    int b = i >> 4;
    int f = i & 15;
    x_buf[i] = s * x_in[(b * OBS_ + (OBS_ - 1)) * F_ + f];
  }
}

// ---------------------------------------------------------------------------
// weight conversion fp32 -> f16 + bias sums (bih + bhh)
// ---------------------------------------------------------------------------
struct ConvArgs {
  const float* src[8];
  f16*         dst[8];
  int          n[8];
  const float* b1[4];
  const float* b2[4];
  float*       bd[4];
};

__global__ void convw(ConvArgs a)
{
  int gid = blockIdx.x * blockDim.x + threadIdx.x;
  int gs  = gridDim.x * blockDim.x;
#pragma unroll
  for (int s = 0; s < 8; ++s) {
    int n4 = a.n[s] >> 2;
    for (int i = gid; i < n4; i += gs) {
      float4 v = ((const float4*)a.src[s])[i];
      f16x4 d = {(f16)v.x, (f16)v.y, (f16)v.z, (f16)v.w};
      ((f16x4*)a.dst[s])[i] = d;
    }
  }
#pragma unroll
  for (int s = 0; s < 4; ++s) {
    for (int i = gid; i < GN_; i += gs) a.bd[s][i] = a.b1[s][i] + a.b2[s][i];
  }
}

// ---------------------------------------------------------------------------
extern "C" void kernel_launch(void* const* d_in, const int* in_sizes, int n_in,
                              void* d_out, int out_size, void* d_ws, size_t ws_size,
                              hipStream_t stream)
{
  (void)in_sizes; (void)n_in; (void)out_size; (void)ws_size;

  const float* x_in  = (const float*)d_in[0];
  const float* y     = (const float*)d_in[1];
  const float* v_in  = (const float*)d_in[2];
  const float* sx    = (const float*)d_in[3];
  const float* sv    = (const float*)d_in[4];
  const float* vWih0 = (const float*)d_in[5];
  const float* vWhh0 = (const float*)d_in[6];
  const float* vbih0 = (const float*)d_in[7];
  const float* vbhh0 = (const float*)d_in[8];
  const float* vWih1 = (const float*)d_in[9];
  const float* vWhh1 = (const float*)d_in[10];
  const float* vbih1 = (const float*)d_in[11];
  const float* vbhh1 = (const float*)d_in[12];
  const float* vWl   = (const float*)d_in[13];
  const float* vbl   = (const float*)d_in[14];
  const float* aWih0 = (const float*)d_in[15];
  const float* aWhh0 = (const float*)d_in[16];
  const float* abih0 = (const float*)d_in[17];
  const float* abhh0 = (const float*)d_in[18];
  const float* aWih1 = (const float*)d_in[19];
  const float* aWhh1 = (const float*)d_in[20];
  const float* abih1 = (const float*)d_in[21];
  const float* abhh1 = (const float*)d_in[22];
  const float* aWl   = (const float*)d_in[23];
  const float* abl   = (const float*)d_in[24];
  float* out = (float*)d_out;

  char* ws = (char*)d_ws;
  size_t off = 0;
  auto alloc = [&](size_t bytes) {
    char* p = ws + off;
    off += (bytes + 255) & ~(size_t)255;
    return p;
  };
  f16* vWih0f = (f16*)alloc((size_t)GN_ * F_ * 2);
  f16* vWhh0f = (f16*)alloc((size_t)GN_ * H_ * 2);
  f16* vWih1f = (f16*)alloc((size_t)GN_ * H_ * 2);
  f16* vWhh1f = (f16*)alloc((size_t)GN_ * H_ * 2);
  f16* aWih0f = (f16*)alloc((size_t)GN_ * F_ * 2);
  f16* aWhh0f = (f16*)alloc((size_t)GN_ * H_ * 2);
  f16* aWih1f = (f16*)alloc((size_t)GN_ * H_ * 2);
  f16* aWhh1f = (f16*)alloc((size_t)GN_ * H_ * 2);
  float* vb0 = (float*)alloc(GN_ * 4);
  float* vb1 = (float*)alloc(GN_ * 4);
  float* ab0 = (float*)alloc(GN_ * 4);
  float* ab1 = (float*)alloc(GN_ * 4);
  f16* m16 = (f16*)alloc((size_t)OBS_ * 4096 * F_ * 2);
  f16* h0a = (f16*)alloc((size_t)4096 * H_ * 2);
  f16* h0b = (f16*)alloc((size_t)4096 * H_ * 2);
  f16* h1a = (f16*)alloc((size_t)4096 * H_ * 2);
  f16* h1b = (f16*)alloc((size_t)4096 * H_ * 2);
  float* c0 = (float*)alloc((size_t)4096 * H_ * 4);
  float* c1 = (float*)alloc((size_t)4096 * H_ * 4);
  f16* a16   = (f16*)alloc((size_t)B_ * F_ * 2);
  float* v_buf = (float*)alloc((size_t)B_ * F_ * 4);
  float* x_buf = (float*)alloc((size_t)B_ * F_ * 4);
  unsigned* bar = (unsigned*)alloc(256);

  hipMemsetAsync(bar, 0, 256, stream);

  ConvArgs ca;
  ca.src[0] = vWih0; ca.dst[0] = vWih0f; ca.n[0] = GN_ * F_;
  ca.src[1] = vWhh0; ca.dst[1] = vWhh0f; ca.n[1] = GN_ * H_;
  ca.src[2] = vWih1; ca.dst[2] = vWih1f; ca.n[2] = GN_ * H_;
  ca.src[3] = vWhh1; ca.dst[3] = vWhh1f; ca.n[3] = GN_ * H_;
  ca.src[4] = aWih0; ca.dst[4] = aWih0f; ca.n[4] = GN_ * F_;
  ca.src[5] = aWhh0; ca.dst[5] = aWhh0f; ca.n[5] = GN_ * H_;
  ca.src[6] = aWih1; ca.dst[6] = aWih1f; ca.n[6] = GN_ * H_;
  ca.src[7] = aWhh1; ca.dst[7] = aWhh1f; ca.n[7] = GN_ * H_;
  ca.b1[0] = vbih0; ca.b2[0] = vbhh0; ca.bd[0] = vb0;
  ca.b1[1] = vbih1; ca.b2[1] = vbhh1; ca.bd[1] = vb1;
  ca.b1[2] = abih0; ca.b2[2] = abhh0; ca.bd[2] = ab0;
  ca.b1[3] = abih1; ca.b2[3] = abhh1; ca.bd[3] = ab1;
  convw<<<1024, 256, 0, stream>>>(ca);
  prep_kernel<<<1024, 256, 0, stream>>>(x_in, y, v_in, sx, out, x_buf, m16);

  // ---- observation phase: v/a chains merged along batch ----
  f16 *h0cur = h0a, *h1cur = h1a;
  const f16 *h0prev = nullptr, *h1prev = nullptr;
  for (int t = 0; t < OBS_; ++t) {
    int grid = (t < OBS_ - 1) ? 1024 : 512;   // t=19: v-only
    h0cur = (t & 1) ? h0b : h0a;
    h1cur = (t & 1) ? h1b : h1a;

    StepArgs q{};
    q.A16 = m16 + (size_t)t * 4096 * F_;
    q.W16v = vWih0f; q.W16a = aWih0f;
    q.bv = vb0; q.ba = ab0;
    q.cout = c0; q.hout = h0cur;
    if (t == 0) {
      lstm_step<1, 0, 0, 1><<<grid, 256, 0, stream>>>(q);
    } else {
      q.A0 = h0prev; q.W0v = vWhh0f; q.W0a = aWhh0f; q.cin = c0;
      lstm_step<1, 1, 1, 1><<<grid, 256, 0, stream>>>(q);
    }

    StepArgs r{};
    r.A0 = h0cur; r.W0v = vWih1f; r.W0a = aWih1f;
    r.bv = vb1; r.ba = ab1;
    r.cout = c1; r.hout = h1cur;
    if (t == 0) {
      lstm_step<0, 1, 0, 1><<<grid, 256, 0, stream>>>(r);
    } else {
      r.A1 = h1prev; r.W1v = vWhh1f; r.W1a = aWhh1f; r.cin = c1;
      lstm_step<0, 2, 1, 1><<<grid, 256, 0, stream>>>(r);
    }
    h0prev = h0cur; h1prev = h1cur;
  }

  // v-head (h1 of t=19 is in h1cur, v rows 0..2047)
  proj_update<0><<<128, 256, 0, stream>>>(h1cur, vWl, vbl, sv, v_buf, nullptr, nullptr, nullptr);
  // a-head (h1 of t=18 is in h1a since 18 is even; a rows at +2048)
  proj_update<1><<<128, 256, 0, stream>>>(h1a + (size_t)2048 * H_, aWl, abl, sv,
                                          v_buf, x_buf, out, a16);

  // ---- autoregressive scan: single persistent kernel ----
  ScanArgs sa{};
  sa.Wih0 = aWih0f; sa.Wih1 = aWih1f; sa.b0g = ab0; sa.b1g = ab1;
  sa.Wl = aWl; sa.bl = abl; sa.sv = sv;
  sa.a16 = a16; sa.v_buf = v_buf; sa.x_buf = x_buf; sa.out = out;
  sa.h0 = h0a; sa.h1 = h1a; sa.bar = bar;
  scan_kernel<<<512, 256, 0, stream>>>(sa);
}

// Round 5
// 4394.708 us; speedup vs baseline: 2.1089x; 2.1089x over previous
//
#include <hip/hip_runtime.h>

// ---------------------------------------------------------------------------
// Two 2-layer LSTMs (H=1024) + 29-step autoregressive scan (state resets each
// step => scan needs only Wih matmuls). f16 MFMA 16x16x32, fp32 accumulate,
// gates fused in GEMM epilogue.
// Round 3/4 (resubmit x2 after GPU-acquisition timeouts): counted-vmcnt
// pipelined K-loop (T4), obs {l0(t) || l1(t-1)} pair dispatches, scan = 2
// launches/step with proj fused into layer1 (ppart partials, summed in next
// step's layer0 kernel). No grid-wide atomics.
// ---------------------------------------------------------------------------

#define B_    2048
#define OBS_  20
#define PRED_ 30
#define F_    16
#define H_    1024
#define GN_   4096   // 4*H

typedef _Float16 f16;
typedef _Float16 f16x8 __attribute__((ext_vector_type(8)));
typedef _Float16 f16x4 __attribute__((ext_vector_type(4)));
typedef float    f32x4 __attribute__((ext_vector_type(4)));

__device__ __forceinline__ float fast_sigmoid(float x) {
  return 1.0f / (1.0f + __expf(-x));
}
__device__ __forceinline__ float fast_tanh(float x) {
  float ax = fabsf(x);
  float e  = __expf(-2.0f * ax);
  float r  = (1.0f - e) / (1.0f + e);
  return copysignf(r, x);
}

// ---------------------------------------------------------------------------
// GEMM building blocks (BK=32, tile 128 rows x 32 j-cols, 4 waves 2x2)
// LDS tile [128][32] f16 = 8KB; 4 16B slots/row; swizzle slot ^= (row>>1)&3.
// Staged via global_load_lds (linear LDS dest, inverse-swizzled global src).
// ---------------------------------------------------------------------------
__device__ __forceinline__ void stageA(f16* dst, const f16* Asrc, int b0, int k0, int tid) {
#pragma unroll
  for (int cc = 0; cc < 2; ++cc) {
    int o  = cc * 4096 + tid * 16;
    int rr = o >> 6;
    int sp = (o >> 4) & 3;
    int sl = sp ^ ((rr >> 1) & 3);
    const f16* gp = Asrc + (size_t)(b0 + rr) * H_ + k0 + sl * 8;
    __builtin_amdgcn_global_load_lds(
        (const __attribute__((address_space(1))) void*)gp,
        (__attribute__((address_space(3))) void*)((char*)dst + o), 16, 0, 0);
  }
}
__device__ __forceinline__ void stageB(f16* dst, const f16* Wsrc, int j0, int k0, int tid) {
#pragma unroll
  for (int cc = 0; cc < 2; ++cc) {
    int o  = cc * 4096 + tid * 16;
    int rr = o >> 6;
    int sp = (o >> 4) & 3;
    int sl = sp ^ ((rr >> 1) & 3);
    int row = (rr >> 5) * H_ + j0 + (rr & 31);     // gate*1024 + j
    const f16* gp = Wsrc + (size_t)row * H_ + k0 + sl * 8;
    __builtin_amdgcn_global_load_lds(
        (const __attribute__((address_space(1))) void*)gp,
        (__attribute__((address_space(3))) void*)((char*)dst + o), 16, 0, 0);
  }
}

__device__ __forceinline__ void acc_init(f32x4 (&acc)[4][4], const float* bias, int jcol) {
#pragma unroll
  for (int g = 0; g < 4; ++g) {
    float bv = bias[g * H_ + jcol];
#pragma unroll
    for (int m = 0; m < 4; ++m) acc[m][g] = (f32x4){bv, bv, bv, bv};
  }
}

// K=16 input term, zero-padded to one K=32 MFMA slice (A from global)
__device__ __forceinline__ void run_k16(f32x4 (&acc)[4][4], const f16* A16, const f16* W16,
    int b0, int j0, int wr, int wc, int lcol, int lkq)
{
  f16x8 za = {0, 0, 0, 0, 0, 0, 0, 0};
  f16x8 af[4], bf[4];
#pragma unroll
  for (int m = 0; m < 4; ++m) {
    if (lkq < 2) {
      int row = b0 + wr * 64 + m * 16 + lcol;
      af[m] = *(const f16x8*)(A16 + (size_t)row * 16 + lkq * 8);
    } else af[m] = za;
  }
#pragma unroll
  for (int g = 0; g < 4; ++g) {
    if (lkq < 2) {
      int row = g * H_ + j0 + wc * 16 + lcol;
      bf[g] = *(const f16x8*)(W16 + (size_t)row * 16 + lkq * 8);
    } else bf[g] = za;
  }
#pragma unroll
  for (int m = 0; m < 4; ++m)
#pragma unroll
    for (int g = 0; g < 4; ++g)
      acc[m][g] = __builtin_amdgcn_mfma_f32_16x16x32_f16(af[m], bf[g], acc[m][g], 0, 0, 0);
}

__device__ __forceinline__ void kstep_mfma(f32x4 (&acc)[4][4], const f16* lA, const f16* lB,
    int wr, int wc, int lcol, int lkq)
{
  f16x8 av[4], bw[4];
#pragma unroll
  for (int m = 0; m < 4; ++m) {
    int ar = wr * 64 + m * 16 + lcol;
    int sa = lkq ^ ((ar >> 1) & 3);
    av[m] = *(const f16x8*)&lA[ar * 32 + sa * 8];
  }
#pragma unroll
  for (int g = 0; g < 4; ++g) {
    int br = g * 32 + wc * 16 + lcol;
    int sb = lkq ^ ((br >> 1) & 3);
    bw[g] = *(const f16x8*)&lB[br * 32 + sb * 8];
  }
#pragma unroll
  for (int m = 0; m < 4; ++m)
#pragma unroll
    for (int g = 0; g < 4; ++g)
      acc[m][g] = __builtin_amdgcn_mfma_f32_16x16x32_f16(av[m], bw[g], acc[m][g], 0, 0, 0);
}

// Pipelined K loop (counted vmcnt, loads stay in flight across barriers).
// Caller must have staged tile 0. Per wave per tile: 4 vmem instrs =>
// vmcnt(4) waits exactly for tile t while tile t+1 flies.
__device__ __forceinline__ void run_kloop_rt(f32x4 (&acc)[4][4],
    f16 (*lA)[4096], f16 (*lB)[4096],
    const f16* A0, const f16* W0, const f16* A1, const f16* W1,
    int NT, int NTSW,
    int b0, int j0, int tid, int wr, int wc, int lcol, int lkq)
{
  int cur = 0;
  for (int t = 0; t < NT; ++t) {
    if (t + 1 < NT) {
      int tn = t + 1;
      const f16* As = (tn >= NTSW) ? A1 : A0;
      const f16* Ws = (tn >= NTSW) ? W1 : W0;
      int k0 = (tn & 31) * 32;
      stageA(lA[cur ^ 1], As, b0, k0, tid);
      stageB(lB[cur ^ 1], Ws, j0, k0, tid);
      asm volatile("s_waitcnt vmcnt(4)\n\ts_barrier" ::: "memory");
    } else {
      asm volatile("s_waitcnt vmcnt(0)\n\ts_barrier" ::: "memory");
    }
    kstep_mfma(acc, lA[cur], lB[cur], wr, wc, lcol, lkq);
    asm volatile("s_waitcnt lgkmcnt(0)\n\ts_barrier" ::: "memory");
    cur ^= 1;
  }
}

__device__ __forceinline__ void lstm_epi_g(f32x4 (&acc)[4][4], const float* cin, float* cout,
    f16* hout, int b0, int jcol, int wr, int lkq, int hasc, int writec)
{
#pragma unroll
  for (int m = 0; m < 4; ++m) {
    int brow0 = b0 + wr * 64 + m * 16 + lkq * 4;
#pragma unroll
    for (int r = 0; r < 4; ++r) {
      size_t bi = (size_t)(brow0 + r) * H_ + jcol;
      float gi = acc[m][0][r], gf = acc[m][1][r], gg = acc[m][2][r], go = acc[m][3][r];
      float cold = hasc ? cin[bi] : 0.0f;
      float cn = fast_sigmoid(gf) * cold + fast_sigmoid(gi) * fast_tanh(gg);
      float hv = fast_sigmoid(go) * fast_tanh(cn);
      if (writec) cout[bi] = cn;
      hout[bi] = (f16)hv;
    }
  }
}

// ---------------------------------------------------------------------------
// generic LSTM-step body; v/a chains split along batch (ch = bm>>4)
// ---------------------------------------------------------------------------
struct StepArgs {
  const f16* A16; const f16* W16v; const f16* W16a;
  const f16* A0;  const f16* W0v;  const f16* W0a;
  const f16* A1;  const f16* W1v;  const f16* W1a;
  const float* bv; const float* ba;
  const float* cin; float* cout; f16* hout;
  int k16, nt, hasc, writec;
};

__device__ __forceinline__ void lstm_body(const StepArgs& p, f16 (*lA)[4096], f16 (*lB)[4096], int bi)
{
  const int tid = threadIdx.x, lane = tid & 63;
  const int wv = tid >> 6, wr = wv >> 1, wc = wv & 1;
  const int bm = bi >> 5, bn = bi & 31;
  const int b0 = bm * 128, j0 = bn * 32;
  const int ch = bm >> 4;
  const int lcol = lane & 15, lkq = lane >> 4;
  const int jcol = j0 + wc * 16 + lcol;

  const f16* W16 = ch ? p.W16a : p.W16v;
  const f16* W0  = ch ? p.W0a  : p.W0v;
  const f16* W1  = ch ? p.W1a  : p.W1v;
  const float* bias = ch ? p.ba : p.bv;

  if (p.nt) { stageA(lA[0], p.A0, b0, 0, tid); stageB(lB[0], W0, j0, 0, tid); }
  f32x4 acc[4][4];
  acc_init(acc, bias, jcol);
  if (p.k16) run_k16(acc, p.A16, W16, b0, j0, wr, wc, lcol, lkq);
  if (p.nt)
    run_kloop_rt(acc, lA, lB, p.A0, W0, p.A1, W1, p.nt, 32, b0, j0, tid, wr, wc, lcol, lkq);
  lstm_epi_g(acc, p.cin, p.cout, p.hout, b0, jcol, wr, lkq, p.hasc, p.writec);
}

// obs dispatch: blocks [0,split) run q (layer0 step t), rest run r (layer1 step t-1)
__global__ __launch_bounds__(256, 4)
void obs_pair(StepArgs q, StepArgs r, int split)
{
  __shared__ f16 lA[2][4096];
  __shared__ f16 lB[2][4096];
  int blk = blockIdx.x;
  if (blk < split) lstm_body(q, lA, lB, blk);
  else             lstm_body(r, lA, lB, blk - split);
}

// ---------------------------------------------------------------------------
// scan layer1 + fused proj partial:
//   h1_tile -> LDS; ppart[row][32 slices][16 f] += h1_tile @ Wl_slice^T
// h1/c never written to global.
// ---------------------------------------------------------------------------
__global__ __launch_bounds__(256, 4)
void scan_l1(const f16* __restrict__ h0, const f16* __restrict__ Wih1,
             const float* __restrict__ bias1, const float* __restrict__ Wl,
             float* __restrict__ ppart)
{
  __shared__ f16 lA[2][4096];
  __shared__ f16 lB[2][4096];
  __shared__ f16 hl[128 * 40];   // stride 40 f16 = 80B: 2-way banks on b128 reads
  const int tid = threadIdx.x, lane = tid & 63;
  const int wv = tid >> 6, wr = wv >> 1, wc = wv & 1;
  const int bm = blockIdx.x >> 5, bn = blockIdx.x & 31;
  const int b0 = bm * 128, j0 = bn * 32;
  const int lcol = lane & 15, lkq = lane >> 4;
  const int jcol = j0 + wc * 16 + lcol;

  stageA(lA[0], h0, b0, 0, tid);
  stageB(lB[0], Wih1, j0, 0, tid);
  f32x4 acc[4][4];
  acc_init(acc, bias1, jcol);
  run_kloop_rt(acc, lA, lB, h0, Wih1, nullptr, nullptr, 32, 32, b0, j0, tid, wr, wc, lcol, lkq);

  // epilogue -> LDS h tile (zero cell state)
  int jl = wc * 16 + lcol;
#pragma unroll
  for (int m = 0; m < 4; ++m) {
#pragma unroll
    for (int r = 0; r < 4; ++r) {
      int row = wr * 64 + m * 16 + lkq * 4 + r;
      float gi = acc[m][0][r], gf = acc[m][1][r], gg = acc[m][2][r], go = acc[m][3][r];
      (void)gf;
      float cn = fast_sigmoid(gi) * fast_tanh(gg);
      float hv = fast_sigmoid(go) * fast_tanh(cn);
      hl[row * 40 + jl] = (f16)hv;
    }
  }
  __syncthreads();

  // proj partial: [128,32] @ Wl[:, j0:j0+32]^T -> [128,16], via 2 MFMA per wave
  const float* wrow = Wl + (size_t)lcol * H_ + j0 + lkq * 8;
  float4 w0 = *(const float4*)wrow, w1 = *(const float4*)(wrow + 4);
  f16x8 bf = {(f16)w0.x, (f16)w0.y, (f16)w0.z, (f16)w0.w,
              (f16)w1.x, (f16)w1.y, (f16)w1.z, (f16)w1.w};
#pragma unroll
  for (int mt = 0; mt < 2; ++mt) {
    int arow = wv * 32 + mt * 16 + lcol;
    f16x8 af = *(const f16x8*)&hl[arow * 40 + lkq * 8];
    f32x4 pc = {0, 0, 0, 0};
    pc = __builtin_amdgcn_mfma_f32_16x16x32_f16(af, bf, pc, 0, 0, 0);
#pragma unroll
    for (int r = 0; r < 4; ++r) {
      int row = b0 + wv * 32 + mt * 16 + lkq * 4 + r;
      ppart[(size_t)row * 512 + bn * 16 + lcol] = pc[r];
    }
  }
}

// ---------------------------------------------------------------------------
// scan layer0 + finalize of previous step's proj:
//   a = tanh(sum_slices ppart + bl); (bn==0): v += sv*a; x += v; out = x
//   then gates = a @ Wih0^T (K=16) -> h0
// ---------------------------------------------------------------------------
template<int FIRST, int LAST>
__global__ __launch_bounds__(256, 4)
void scan_l0(const float* __restrict__ ppart, const f16* __restrict__ a16f,
             const float* __restrict__ bl, const float* __restrict__ sv,
             float* __restrict__ v_buf, float* __restrict__ x_buf,
             float* __restrict__ out_t,
             const float* __restrict__ bias0, const f16* __restrict__ Wih0,
             f16* __restrict__ h0out)
{
  __shared__ f16 a_lds[128 * 16];
  const int tid = threadIdx.x;
  const int bm = LAST ? (int)blockIdx.x : (int)(blockIdx.x >> 5);
  const int bn = LAST ? 0 : (int)(blockIdx.x & 31);
  const int b0 = bm * 128;

  const int ebase = tid * 8;        // 8 of 2048 tile elems
  const int erow  = ebase >> 4;     // 0..127
  const int ef0   = ebase & 15;     // 0 or 8
  float av[8];
  if (FIRST) {
    f16x8 a8 = *(const f16x8*)&a16f[(size_t)(b0 + erow) * 16 + ef0];
#pragma unroll
    for (int e = 0; e < 8; ++e) av[e] = (float)a8[e];
  } else {
    f32x4 s0 = {0, 0, 0, 0}, s1 = {0, 0, 0, 0};
    const float* pp = ppart + (size_t)(b0 + erow) * 512 + ef0;
#pragma unroll
    for (int sN = 0; sN < 32; ++sN) {
      s0 += *(const f32x4*)(pp + sN * 16);
      s1 += *(const f32x4*)(pp + sN * 16 + 4);
    }
#pragma unroll
    for (int e = 0; e < 4; ++e) av[e] = fast_tanh(s0[e] + bl[ef0 + e]);
#pragma unroll
    for (int e = 0; e < 4; ++e) av[4 + e] = fast_tanh(s1[e] + bl[ef0 + 4 + e]);
    if (bn == 0) {
      float svv = sv[0];
#pragma unroll
      for (int e = 0; e < 8; ++e) {
        int idx = (b0 + erow) * F_ + ef0 + e;
        float v = v_buf[idx] + svv * av[e];
        v_buf[idx] = v;
        float x = x_buf[idx] + v;
        x_buf[idx] = x;
        out_t[idx] = x;
      }
    }
  }

  if (!LAST) {
    f16x8 a8;
#pragma unroll
    for (int e = 0; e < 8; ++e) a8[e] = (f16)av[e];
    *(f16x8*)&a_lds[ebase] = a8;            // row-major [128][16]
    __syncthreads();

    const int lane = tid & 63;
    const int wv = tid >> 6, wr = wv >> 1, wc = wv & 1;
    const int lcol = lane & 15, lkq = lane >> 4;
    const int j0 = bn * 32, jcol = j0 + wc * 16 + lcol;
    f32x4 acc[4][4];
    acc_init(acc, bias0, jcol);
    f16x8 za = {0, 0, 0, 0, 0, 0, 0, 0};
    f16x8 af[4], bf[4];
#pragma unroll
    for (int m = 0; m < 4; ++m) {
      if (lkq < 2) {
        int arow = wr * 64 + m * 16 + lcol;
        af[m] = *(const f16x8*)&a_lds[arow * 16 + lkq * 8];
      } else af[m] = za;
    }
#pragma unroll
    for (int g = 0; g < 4; ++g) {
      if (lkq < 2) {
        int brow = g * H_ + j0 + wc * 16 + lcol;
        bf[g] = *(const f16x8*)(Wih0 + (size_t)brow * 16 + lkq * 8);
      } else bf[g] = za;
    }
#pragma unroll
    for (int m = 0; m < 4; ++m)
#pragma unroll
      for (int g = 0; g < 4; ++g)
        acc[m][g] = __builtin_amdgcn_mfma_f32_16x16x32_f16(af[m], bf[g], acc[m][g], 0, 0, 0);
    lstm_epi_g(acc, nullptr, nullptr, h0out, b0, jcol, wr, lkq, 0, 0);
  }
}

// ---------------------------------------------------------------------------
// obs-phase projection heads (unchanged)
// ---------------------------------------------------------------------------
template<int MODE>
__global__ __launch_bounds__(256)
void proj_update(const f16* __restrict__ h1, const float* __restrict__ Wl,
                 const float* __restrict__ bl, const float* __restrict__ sv,
                 float* __restrict__ v_buf, float* __restrict__ x_buf,
                 float* __restrict__ out_t, f16* __restrict__ a16)
{
  __shared__ f16 lh[16 * 1024];
  const int b0r = blockIdx.x * 16;
  const int tid = threadIdx.x;
#pragma unroll
  for (int c = 0; c < 8; ++c) {
    int o = c * 256 + tid;
    *(f16x8*)&lh[o * 8] = *(const f16x8*)&h1[(size_t)b0r * 1024 + o * 8];
  }
  __syncthreads();
  const int br = tid >> 4;
  const int f  = tid & 15;
  float s0 = 0, s1 = 0, s2 = 0, s3 = 0;
  const float4* wp = (const float4*)(Wl + (size_t)f * 1024);
#pragma unroll 4
  for (int k8 = 0; k8 < 128; ++k8) {
    f16x8 hv = *(const f16x8*)&lh[br * 1024 + k8 * 8];
    float4 w0 = wp[k8 * 2], w1 = wp[k8 * 2 + 1];
    s0 += (float)hv[0] * w0.x + (float)hv[4] * w1.x;
    s1 += (float)hv[1] * w0.y + (float)hv[5] * w1.y;
    s2 += (float)hv[2] * w0.z + (float)hv[6] * w1.z;
    s3 += (float)hv[3] * w0.w + (float)hv[7] * w1.w;
  }
  float t = fast_tanh(bl[f] + ((s0 + s1) + (s2 + s3)));
  int idx = (b0r + br) * F_ + f;
  if (MODE == 0) {
    v_buf[idx] = sv[0] * t;
  } else {
    float v = v_buf[idx] + sv[0] * t;
    v_buf[idx] = v;
    float x = x_buf[idx] + v;
    x_buf[idx] = x;
    out_t[idx] = x;
    a16[idx] = (f16)t;
  }
}

// ---------------------------------------------------------------------------
// input prep (merged m16 [t][4096][16]: rows 0-2047 v_seq, 2048+ a_seq)
// ---------------------------------------------------------------------------
__global__ void prep_kernel(const float* __restrict__ x_in, const float* __restrict__ y,
                            const float* __restrict__ v_in, const float* __restrict__ sx,
                            float* __restrict__ out, float* __restrict__ x_buf,
                            f16* __restrict__ m16)
{
  const float s = sx[0];
  int gid = blockIdx.x * blockDim.x + threadIdx.x;
  int gs  = gridDim.x * blockDim.x;
  for (int i = gid; i < B_ * OBS_ * F_; i += gs) {
    int b = i / (OBS_ * F_);
    int rem = i - b * (OBS_ * F_);
    int t = rem >> 4;
    int f = rem & 15;
    float v = v_in[i];
    m16[((size_t)t * 4096 + b) * F_ + f] = (f16)v;
    if (t < OBS_ - 1)
      m16[((size_t)t * 4096 + 2048 + b) * F_ + f] = (f16)(v_in[i + F_] - v);
  }
  for (int i = gid; i < PRED_ * B_ * F_; i += gs) {
    int t = i / (B_ * F_);
    int rem = i - t * (B_ * F_);
    int b = rem >> 4;
    int f = rem & 15;
    out[PRED_ * B_ * F_ + i] = s * y[(b * PRED_ + t) * F_ + f];
  }
  for (int i = gid; i < B_ * F_; i += gs) {
    int b = i >> 4;
    int f = i & 15;
    x_buf[i] = s * x_in[(b * OBS_ + (OBS_ - 1)) * F_ + f];
  }
}

// ---------------------------------------------------------------------------
// weight conversion fp32 -> f16 + bias sums
// ---------------------------------------------------------------------------
struct ConvArgs {
  const float* src[8];
  f16*         dst[8];
  int          n[8];
  const float* b1[4];
  const float* b2[4];
  float*       bd[4];
};

__global__ void convw(ConvArgs a)
{
  int gid = blockIdx.x * blockDim.x + threadIdx.x;
  int gs  = gridDim.x * blockDim.x;
#pragma unroll
  for (int s = 0; s < 8; ++s) {
    int n4 = a.n[s] >> 2;
    for (int i = gid; i < n4; i += gs) {
      float4 v = ((const float4*)a.src[s])[i];
      f16x4 d = {(f16)v.x, (f16)v.y, (f16)v.z, (f16)v.w};
      ((f16x4*)a.dst[s])[i] = d;
    }
  }
#pragma unroll
  for (int s = 0; s < 4; ++s) {
    for (int i = gid; i < GN_; i += gs) a.bd[s][i] = a.b1[s][i] + a.b2[s][i];
  }
}

// ---------------------------------------------------------------------------
extern "C" void kernel_launch(void* const* d_in, const int* in_sizes, int n_in,
                              void* d_out, int out_size, void* d_ws, size_t ws_size,
                              hipStream_t stream)
{
  (void)in_sizes; (void)n_in; (void)out_size; (void)ws_size;

  const float* x_in  = (const float*)d_in[0];
  const float* y     = (const float*)d_in[1];
  const float* v_in  = (const float*)d_in[2];
  const float* sx    = (const float*)d_in[3];
  const float* sv    = (const float*)d_in[4];
  const float* vWih0 = (const float*)d_in[5];
  const float* vWhh0 = (const float*)d_in[6];
  const float* vbih0 = (const float*)d_in[7];
  const float* vbhh0 = (const float*)d_in[8];
  const float* vWih1 = (const float*)d_in[9];
  const float* vWhh1 = (const float*)d_in[10];
  const float* vbih1 = (const float*)d_in[11];
  const float* vbhh1 = (const float*)d_in[12];
  const float* vWl   = (const float*)d_in[13];
  const float* vbl   = (const float*)d_in[14];
  const float* aWih0 = (const float*)d_in[15];
  const float* aWhh0 = (const float*)d_in[16];
  const float* abih0 = (const float*)d_in[17];
  const float* abhh0 = (const float*)d_in[18];
  const float* aWih1 = (const float*)d_in[19];
  const float* aWhh1 = (const float*)d_in[20];
  const float* abih1 = (const float*)d_in[21];
  const float* abhh1 = (const float*)d_in[22];
  const float* aWl   = (const float*)d_in[23];
  const float* abl   = (const float*)d_in[24];
  float* out = (float*)d_out;

  char* ws = (char*)d_ws;
  size_t off = 0;
  auto alloc = [&](size_t bytes) {
    char* p = ws + off;
    off += (bytes + 255) & ~(size_t)255;
    return p;
  };
  f16* vWih0f = (f16*)alloc((size_t)GN_ * F_ * 2);
  f16* vWhh0f = (f16*)alloc((size_t)GN_ * H_ * 2);
  f16* vWih1f = (f16*)alloc((size_t)GN_ * H_ * 2);
  f16* vWhh1f = (f16*)alloc((size_t)GN_ * H_ * 2);
  f16* aWih0f = (f16*)alloc((size_t)GN_ * F_ * 2);
  f16* aWhh0f = (f16*)alloc((size_t)GN_ * H_ * 2);
  f16* aWih1f = (f16*)alloc((size_t)GN_ * H_ * 2);
  f16* aWhh1f = (f16*)alloc((size_t)GN_ * H_ * 2);
  float* vb0 = (float*)alloc(GN_ * 4);
  float* vb1 = (float*)alloc(GN_ * 4);
  float* ab0 = (float*)alloc(GN_ * 4);
  float* ab1 = (float*)alloc(GN_ * 4);
  f16* m16 = (f16*)alloc((size_t)OBS_ * 4096 * F_ * 2);
  f16* h0a = (f16*)alloc((size_t)4096 * H_ * 2);
  f16* h0b = (f16*)alloc((size_t)4096 * H_ * 2);
  f16* h1a = (f16*)alloc((size_t)4096 * H_ * 2);
  f16* h1b = (f16*)alloc((size_t)4096 * H_ * 2);
  float* c0 = (float*)alloc((size_t)4096 * H_ * 4);
  float* c1 = (float*)alloc((size_t)4096 * H_ * 4);
  f16* a16   = (f16*)alloc((size_t)B_ * F_ * 2);
  float* v_buf = (float*)alloc((size_t)B_ * F_ * 4);
  float* x_buf = (float*)alloc((size_t)B_ * F_ * 4);
  float* ppart = (float*)alloc((size_t)B_ * 32 * F_ * 4);   // [2048][32][16]

  ConvArgs ca;
  ca.src[0] = vWih0; ca.dst[0] = vWih0f; ca.n[0] = GN_ * F_;
  ca.src[1] = vWhh0; ca.dst[1] = vWhh0f; ca.n[1] = GN_ * H_;
  ca.src[2] = vWih1; ca.dst[2] = vWih1f; ca.n[2] = GN_ * H_;
  ca.src[3] = vWhh1; ca.dst[3] = vWhh1f; ca.n[3] = GN_ * H_;
  ca.src[4] = aWih0; ca.dst[4] = aWih0f; ca.n[4] = GN_ * F_;
  ca.src[5] = aWhh0; ca.dst[5] = aWhh0f; ca.n[5] = GN_ * H_;
  ca.src[6] = aWih1; ca.dst[6] = aWih1f; ca.n[6] = GN_ * H_;
  ca.src[7] = aWhh1; ca.dst[7] = aWhh1f; ca.n[7] = GN_ * H_;
  ca.b1[0] = vbih0; ca.b2[0] = vbhh0; ca.bd[0] = vb0;
  ca.b1[1] = vbih1; ca.b2[1] = vbhh1; ca.bd[1] = vb1;
  ca.b1[2] = abih0; ca.b2[2] = abhh0; ca.bd[2] = ab0;
  ca.b1[3] = abih1; ca.b2[3] = abhh1; ca.bd[3] = ab1;
  convw<<<1024, 256, 0, stream>>>(ca);
  prep_kernel<<<1024, 256, 0, stream>>>(x_in, y, v_in, sx, out, x_buf, m16);

  auto h0buf = [&](int t) { return (t & 1) ? h0b : h0a; };
  auto h1buf = [&](int t) { return (t & 1) ? h1b : h1a; };
  StepArgs dummy{};

  // ---- obs t=0: layer0 only ----
  {
    StepArgs q{};
    q.A16 = m16; q.W16v = vWih0f; q.W16a = aWih0f;
    q.bv = vb0; q.ba = ab0;
    q.cout = c0; q.hout = h0buf(0);
    q.k16 = 1; q.nt = 0; q.hasc = 0; q.writec = 1;
    obs_pair<<<1024, 256, 0, stream>>>(q, dummy, 1024);
  }

  // ---- obs pairs: {layer0(t) || layer1(t-1)} for t=1..19 ----
  for (int t = 1; t < OBS_; ++t) {
    int u = t - 1;
    StepArgs q{};
    q.A16 = m16 + (size_t)t * 4096 * F_;
    q.W16v = vWih0f; q.W16a = aWih0f;
    q.A0 = h0buf(t - 1); q.W0v = vWhh0f; q.W0a = aWhh0f;
    q.bv = vb0; q.ba = ab0;
    q.cin = c0; q.cout = c0; q.hout = h0buf(t);
    q.k16 = 1; q.nt = 32; q.hasc = 1; q.writec = 1;

    StepArgs r{};
    r.A0 = h0buf(u); r.W0v = vWih1f; r.W0a = aWih1f;
    r.A1 = (u > 0) ? h1buf(u - 1) : nullptr;
    r.W1v = vWhh1f; r.W1a = aWhh1f;
    r.bv = vb1; r.ba = ab1;
    r.cin = c1; r.cout = c1; r.hout = h1buf(u);
    r.k16 = 0; r.nt = (u > 0) ? 64 : 32; r.hasc = (u > 0); r.writec = 1;

    int split = (t == OBS_ - 1) ? 512 : 1024;       // t=19: v-only layer0
    int grid  = (t == OBS_ - 1) ? 1536 : 2048;
    obs_pair<<<grid, 256, 0, stream>>>(q, r, split);
  }

  // ---- obs final: layer1(19), v rows only ----
  {
    StepArgs r{};
    r.A0 = h0buf(19); r.W0v = vWih1f; r.W0a = aWih1f;
    r.A1 = h1buf(18); r.W1v = vWhh1f; r.W1a = aWhh1f;
    r.bv = vb1; r.ba = ab1;
    r.cin = c1; r.cout = c1; r.hout = h1buf(19);
    r.k16 = 0; r.nt = 64; r.hasc = 1; r.writec = 1;
    obs_pair<<<512, 256, 0, stream>>>(dummy, r, 0);
  }

  // heads: v from h1(19); a from h1(18) rows 2048+
  proj_update<0><<<128, 256, 0, stream>>>(h1buf(19), vWl, vbl, sv,
                                          v_buf, nullptr, nullptr, nullptr);
  proj_update<1><<<128, 256, 0, stream>>>(h1buf(18) + (size_t)2048 * H_, aWl, abl, sv,
                                          v_buf, x_buf, out, a16);

  // ---- autoregressive scan: 2 launches/step ----
  scan_l0<1, 0><<<512, 256, 0, stream>>>(ppart, a16, abl, sv, v_buf, x_buf, out,
                                         ab0, aWih0f, h0a);
  scan_l1<<<512, 256, 0, stream>>>(h0a, aWih1f, ab1, aWl, ppart);
  for (int t = 2; t < PRED_; ++t) {
    scan_l0<0, 0><<<512, 256, 0, stream>>>(ppart, nullptr, abl, sv, v_buf, x_buf,
                                           out + (size_t)(t - 1) * B_ * F_,
                                           ab0, aWih0f, h0a);
    scan_l1<<<512, 256, 0, stream>>>(h0a, aWih1f, ab1, aWl, ppart);
  }
  scan_l0<0, 1><<<16, 256, 0, stream>>>(ppart, nullptr, abl, sv, v_buf, x_buf,
                                        out + (size_t)(PRED_ - 1) * B_ * F_,
                                        ab0, aWih0f, h0a);
}

// Round 6
// 4203.770 us; speedup vs baseline: 2.2047x; 1.0454x over previous
//
#include <hip/hip_runtime.h>

// ---------------------------------------------------------------------------
// Two 2-layer LSTMs (H=1024) + 29-step autoregressive scan. f16 MFMA
// 16x16x32, fp32 accumulate, gates fused in GEMM epilogue.
// Round 6: 512-thread blocks (8 waves 2x4), BN=64 (eff N=256), BK=32,
// counted-vmcnt(3) pipeline. 24KB staged per tile serves 128 MFMA
// (2x the MFMA:staging ratio of round 5). LDS 48KB -> 3 blocks/CU.
// Long (layer1) blocks dispatched first (LPT). Scan: 2 launches/step.
// ---------------------------------------------------------------------------

#define B_    2048
#define OBS_  20
#define PRED_ 30
#define F_    16
#define H_    1024
#define GN_   4096   // 4*H

typedef _Float16 f16;
typedef _Float16 f16x8 __attribute__((ext_vector_type(8)));
typedef _Float16 f16x4 __attribute__((ext_vector_type(4)));
typedef float    f32x4 __attribute__((ext_vector_type(4)));

__device__ __forceinline__ float fast_sigmoid(float x) {
  return 1.0f / (1.0f + __expf(-x));
}
__device__ __forceinline__ float fast_tanh(float x) {
  float ax = fabsf(x);
  float e  = __expf(-2.0f * ax);
  float r  = (1.0f - e) / (1.0f + e);
  return copysignf(r, x);
}

// ---------------------------------------------------------------------------
// Tile geometry (512-thread blocks): A tile 128 rows x 32 K (8KB), B tile
// 256 rows (4 gates x 64 j) x 32 K (16KB). 4 16B slots/row; swizzle
// slot ^= (row>>1)&3 => ds_read_b128 2-way bank-aliased (free).
// Staged via global_load_lds: linear LDS dest, inverse-swizzled global src.
// Per thread per tile: 1 (A) + 2 (B) = 3 vmem instrs => vmcnt(3) waits for
// tile t while tile t+1's 3 loads stay in flight.
// ---------------------------------------------------------------------------
__device__ __forceinline__ void stageA512(f16* dst, const f16* Asrc, int b0, int k0, int tid) {
  int o  = tid * 16;                  // 0..8176
  int rr = o >> 6;                    // row 0..127
  int sp = (o >> 4) & 3;
  int sl = sp ^ ((rr >> 1) & 3);
  const f16* gp = Asrc + (size_t)(b0 + rr) * H_ + k0 + sl * 8;
  __builtin_amdgcn_global_load_lds(
      (const __attribute__((address_space(1))) void*)gp,
      (__attribute__((address_space(3))) void*)((char*)dst + o), 16, 0, 0);
}
__device__ __forceinline__ void stageB512(f16* dst, const f16* Wsrc, int j0, int k0, int tid) {
#pragma unroll
  for (int cc = 0; cc < 2; ++cc) {
    int o  = cc * 8192 + tid * 16;
    int rr = o >> 6;                  // row 0..255 (gate*64 + j)
    int sp = (o >> 4) & 3;
    int sl = sp ^ ((rr >> 1) & 3);
    int grow = (rr >> 6) * H_ + j0 + (rr & 63);
    const f16* gp = Wsrc + (size_t)grow * H_ + k0 + sl * 8;
    __builtin_amdgcn_global_load_lds(
        (const __attribute__((address_space(1))) void*)gp,
        (__attribute__((address_space(3))) void*)((char*)dst + o), 16, 0, 0);
  }
}

__device__ __forceinline__ void acc_init(f32x4 (&acc)[4][4], const float* bias, int jcol) {
#pragma unroll
  for (int g = 0; g < 4; ++g) {
    float bv = bias[g * H_ + jcol];
#pragma unroll
    for (int m = 0; m < 4; ++m) acc[m][g] = (f32x4){bv, bv, bv, bv};
  }
}

// K=16 input term, zero-padded to one K=32 MFMA slice (A,B from global)
__device__ __forceinline__ void run_k16(f32x4 (&acc)[4][4], const f16* A16, const f16* W16,
    int b0, int j0, int wr, int wc, int lcol, int lkq)
{
  f16x8 za = {0, 0, 0, 0, 0, 0, 0, 0};
  f16x8 af[4], bf[4];
#pragma unroll
  for (int m = 0; m < 4; ++m) {
    if (lkq < 2) {
      int row = b0 + wr * 64 + m * 16 + lcol;
      af[m] = *(const f16x8*)(A16 + (size_t)row * 16 + lkq * 8);
    } else af[m] = za;
  }
#pragma unroll
  for (int g = 0; g < 4; ++g) {
    if (lkq < 2) {
      int row = g * H_ + j0 + wc * 16 + lcol;
      bf[g] = *(const f16x8*)(W16 + (size_t)row * 16 + lkq * 8);
    } else bf[g] = za;
  }
#pragma unroll
  for (int m = 0; m < 4; ++m)
#pragma unroll
    for (int g = 0; g < 4; ++g)
      acc[m][g] = __builtin_amdgcn_mfma_f32_16x16x32_f16(af[m], bf[g], acc[m][g], 0, 0, 0);
}

__device__ __forceinline__ void kstep_mfma(f32x4 (&acc)[4][4], const f16* lA, const f16* lB,
    int wr, int wc, int lcol, int lkq)
{
  f16x8 av[4], bw[4];
#pragma unroll
  for (int m = 0; m < 4; ++m) {
    int ar = wr * 64 + m * 16 + lcol;
    int sa = lkq ^ ((ar >> 1) & 3);
    av[m] = *(const f16x8*)&lA[ar * 32 + sa * 8];
  }
#pragma unroll
  for (int g = 0; g < 4; ++g) {
    int br = g * 64 + wc * 16 + lcol;
    int sb = lkq ^ ((br >> 1) & 3);
    bw[g] = *(const f16x8*)&lB[br * 32 + sb * 8];
  }
#pragma unroll
  for (int m = 0; m < 4; ++m)
#pragma unroll
    for (int g = 0; g < 4; ++g)
      acc[m][g] = __builtin_amdgcn_mfma_f32_16x16x32_f16(av[m], bw[g], acc[m][g], 0, 0, 0);
}

// Pipelined K loop, counted vmcnt(3): tile t+1's loads fly across barriers.
__device__ __forceinline__ void run_kloop(f32x4 (&acc)[4][4],
    f16 (*lA)[4096], f16 (*lB)[8192],
    const f16* A0, const f16* W0, const f16* A1, const f16* W1,
    int NT, int NTSW,
    int b0, int j0, int tid, int wr, int wc, int lcol, int lkq)
{
  int cur = 0;
  for (int t = 0; t < NT; ++t) {
    if (t + 1 < NT) {
      int tn = t + 1;
      const f16* As = (tn >= NTSW) ? A1 : A0;
      const f16* Ws = (tn >= NTSW) ? W1 : W0;
      int k0 = (tn & 31) * 32;
      stageA512(lA[cur ^ 1], As, b0, k0, tid);
      stageB512(lB[cur ^ 1], Ws, j0, k0, tid);
      asm volatile("s_waitcnt vmcnt(3)\n\ts_barrier" ::: "memory");
    } else {
      asm volatile("s_waitcnt vmcnt(0)\n\ts_barrier" ::: "memory");
    }
    kstep_mfma(acc, lA[cur], lB[cur], wr, wc, lcol, lkq);
    asm volatile("s_waitcnt lgkmcnt(0)\n\ts_barrier" ::: "memory");
    cur ^= 1;
  }
}

__device__ __forceinline__ void lstm_epi_g(f32x4 (&acc)[4][4], const float* cin, float* cout,
    f16* hout, int b0, int jcol, int wr, int lkq, int hasc, int writec)
{
#pragma unroll
  for (int m = 0; m < 4; ++m) {
    int brow0 = b0 + wr * 64 + m * 16 + lkq * 4;
#pragma unroll
    for (int r = 0; r < 4; ++r) {
      size_t bi = (size_t)(brow0 + r) * H_ + jcol;
      float gi = acc[m][0][r], gf = acc[m][1][r], gg = acc[m][2][r], go = acc[m][3][r];
      float cold = hasc ? cin[bi] : 0.0f;
      float cn = fast_sigmoid(gf) * cold + fast_sigmoid(gi) * fast_tanh(gg);
      float hv = fast_sigmoid(go) * fast_tanh(cn);
      if (writec) cout[bi] = cn;
      hout[bi] = (f16)hv;
    }
  }
}

// ---------------------------------------------------------------------------
// generic LSTM-step body; block = (bm, bn16): M-tile 128, j-tile 64.
// v/a chains split along batch (ch = bm>>4).
// ---------------------------------------------------------------------------
struct StepArgs {
  const f16* A16; const f16* W16v; const f16* W16a;
  const f16* A0;  const f16* W0v;  const f16* W0a;
  const f16* A1;  const f16* W1v;  const f16* W1a;
  const float* bv; const float* ba;
  const float* cin; float* cout; f16* hout;
  int k16, nt, hasc, writec;
};

__device__ __forceinline__ void lstm_body(const StepArgs& p, f16 (*lA)[4096], f16 (*lB)[8192], int bi)
{
  const int tid = threadIdx.x, lane = tid & 63;
  const int wv = tid >> 6;               // 0..7
  const int wr = wv >> 2, wc = wv & 3;   // 2 x 4
  const int bm = bi >> 4, bn = bi & 15;
  const int b0 = bm * 128, j0 = bn * 64;
  const int ch = bm >> 4;
  const int lcol = lane & 15, lkq = lane >> 4;
  const int jcol = j0 + wc * 16 + lcol;

  const f16* W16 = ch ? p.W16a : p.W16v;
  const f16* W0  = ch ? p.W0a  : p.W0v;
  const f16* W1  = ch ? p.W1a  : p.W1v;
  const float* bias = ch ? p.ba : p.bv;

  if (p.nt) { stageA512(lA[0], p.A0, b0, 0, tid); stageB512(lB[0], W0, j0, 0, tid); }
  f32x4 acc[4][4];
  acc_init(acc, bias, jcol);
  if (p.k16) run_k16(acc, p.A16, W16, b0, j0, wr, wc, lcol, lkq);
  if (p.nt)
    run_kloop(acc, lA, lB, p.A0, W0, p.A1, W1, p.nt, 32, b0, j0, tid, wr, wc, lcol, lkq);
  lstm_epi_g(acc, p.cin, p.cout, p.hout, b0, jcol, wr, lkq, p.hasc, p.writec);
}

// obs dispatch: blocks [0,split) run rlong (layer1, 2x work — LPT first),
// the rest run qshort (layer0).
__global__ __launch_bounds__(512, 4)
void obs_pair(StepArgs rlong, StepArgs qshort, int split)
{
  __shared__ f16 lA[2][4096];
  __shared__ f16 lB[2][8192];
  int blk = blockIdx.x;
  if (blk < split) lstm_body(rlong, lA, lB, blk);
  else             lstm_body(qshort, lA, lB, blk - split);
}

// ---------------------------------------------------------------------------
// scan layer1 + fused proj partial. 256 blocks (16bm x 16bn), M=2048 (a only).
// h1 -> LDS, then ppart[row][16 slices][16 f] = h_tile @ Wl_slice^T (K=64).
// ---------------------------------------------------------------------------
__global__ __launch_bounds__(512, 2)
void scan_l1(const f16* __restrict__ h0, const f16* __restrict__ Wih1,
             const float* __restrict__ bias1, const float* __restrict__ Wl,
             float* __restrict__ ppart)
{
  __shared__ f16 lA[2][4096];
  __shared__ f16 lB[2][8192];
  __shared__ f16 hl[128 * 72];   // 128 rows x 64 j, stride 72 (bank-spread)
  const int tid = threadIdx.x, lane = tid & 63;
  const int wv = tid >> 6;
  const int wr = wv >> 2, wc = wv & 3;
  const int bm = blockIdx.x >> 4, bn = blockIdx.x & 15;
  const int b0 = bm * 128, j0 = bn * 64;
  const int lcol = lane & 15, lkq = lane >> 4;
  const int jcol = j0 + wc * 16 + lcol;

  stageA512(lA[0], h0, b0, 0, tid);
  stageB512(lB[0], Wih1, j0, 0, tid);
  f32x4 acc[4][4];
  acc_init(acc, bias1, jcol);
  run_kloop(acc, lA, lB, h0, Wih1, nullptr, nullptr, 32, 32, b0, j0, tid, wr, wc, lcol, lkq);

  // epilogue -> LDS h tile (zero cell state)
  int jl = wc * 16 + lcol;
#pragma unroll
  for (int m = 0; m < 4; ++m) {
#pragma unroll
    for (int r = 0; r < 4; ++r) {
      int row = wr * 64 + m * 16 + lkq * 4 + r;
      float gi = acc[m][0][r], gg = acc[m][2][r], go = acc[m][3][r];
      float cn = fast_sigmoid(gi) * fast_tanh(gg);
      float hv = fast_sigmoid(go) * fast_tanh(cn);
      hl[row * 72 + jl] = (f16)hv;
    }
  }
  __syncthreads();

  // proj partial: [128,64] @ Wl[:, j0:j0+64]^T -> [128,16]; wave wv owns
  // rows wv*16..wv*16+15; K=64 via 2 chained MFMAs.
  const float* wp = Wl + (size_t)lcol * H_ + j0 + lkq * 8;
  f16x8 bf0, bf1;
#pragma unroll
  for (int e = 0; e < 8; ++e) { bf0[e] = (f16)wp[e]; bf1[e] = (f16)wp[32 + e]; }
  int arow = wv * 16 + lcol;
  f16x8 af0 = *(const f16x8*)&hl[arow * 72 + lkq * 8];
  f16x8 af1 = *(const f16x8*)&hl[arow * 72 + 32 + lkq * 8];
  f32x4 pc = {0, 0, 0, 0};
  pc = __builtin_amdgcn_mfma_f32_16x16x32_f16(af0, bf0, pc, 0, 0, 0);
  pc = __builtin_amdgcn_mfma_f32_16x16x32_f16(af1, bf1, pc, 0, 0, 0);
#pragma unroll
  for (int r = 0; r < 4; ++r) {
    int prow = b0 + wv * 16 + lkq * 4 + r;
    ppart[(size_t)prow * 256 + bn * 16 + lcol] = pc[r];
  }
}

// ---------------------------------------------------------------------------
// scan layer0 + finalize of previous step's proj. 256-thread blocks,
// grid 512 (16bm x 32bn, j-span 32).
//   a = tanh(sum_16slices ppart + bl); (bn==0): v += sv*a; x += v; out = x
//   then gates = a @ Wih0^T (K=16) -> h0
// ---------------------------------------------------------------------------
template<int FIRST, int LAST>
__global__ __launch_bounds__(256, 4)
void scan_l0(const float* __restrict__ ppart, const f16* __restrict__ a16f,
             const float* __restrict__ bl, const float* __restrict__ sv,
             float* __restrict__ v_buf, float* __restrict__ x_buf,
             float* __restrict__ out_t,
             const float* __restrict__ bias0, const f16* __restrict__ Wih0,
             f16* __restrict__ h0out)
{
  __shared__ f16 a_lds[128 * 16];
  const int tid = threadIdx.x;
  const int bm = LAST ? (int)blockIdx.x : (int)(blockIdx.x >> 5);
  const int bn = LAST ? 0 : (int)(blockIdx.x & 31);
  const int b0 = bm * 128;

  const int ebase = tid * 8;
  const int erow  = ebase >> 4;     // 0..127
  const int ef0   = ebase & 15;     // 0 or 8
  float av[8];
  if (FIRST) {
    f16x8 a8 = *(const f16x8*)&a16f[(size_t)(b0 + erow) * 16 + ef0];
#pragma unroll
    for (int e = 0; e < 8; ++e) av[e] = (float)a8[e];
  } else {
    f32x4 s0 = {0, 0, 0, 0}, s1 = {0, 0, 0, 0};
    const float* pp = ppart + (size_t)(b0 + erow) * 256 + ef0;
#pragma unroll
    for (int sN = 0; sN < 16; ++sN) {
      s0 += *(const f32x4*)(pp + sN * 16);
      s1 += *(const f32x4*)(pp + sN * 16 + 4);
    }
#pragma unroll
    for (int e = 0; e < 4; ++e) av[e] = fast_tanh(s0[e] + bl[ef0 + e]);
#pragma unroll
    for (int e = 0; e < 4; ++e) av[4 + e] = fast_tanh(s1[e] + bl[ef0 + 4 + e]);
    if (bn == 0) {
      float svv = sv[0];
#pragma unroll
      for (int e = 0; e < 8; ++e) {
        int idx = (b0 + erow) * F_ + ef0 + e;
        float v = v_buf[idx] + svv * av[e];
        v_buf[idx] = v;
        float x = x_buf[idx] + v;
        x_buf[idx] = x;
        out_t[idx] = x;
      }
    }
  }

  if (!LAST) {
    f16x8 a8;
#pragma unroll
    for (int e = 0; e < 8; ++e) a8[e] = (f16)av[e];
    *(f16x8*)&a_lds[ebase] = a8;            // row-major [128][16]
    __syncthreads();

    const int lane = tid & 63;
    const int wv = tid >> 6, wr = wv >> 1, wc = wv & 1;
    const int lcol = lane & 15, lkq = lane >> 4;
    const int j0 = bn * 32, jcol = j0 + wc * 16 + lcol;
    f32x4 acc[4][4];
    acc_init(acc, bias0, jcol);
    f16x8 za = {0, 0, 0, 0, 0, 0, 0, 0};
    f16x8 af[4], bf[4];
#pragma unroll
    for (int m = 0; m < 4; ++m) {
      if (lkq < 2) {
        int arow = wr * 64 + m * 16 + lcol;
        af[m] = *(const f16x8*)&a_lds[arow * 16 + lkq * 8];
      } else af[m] = za;
    }
#pragma unroll
    for (int g = 0; g < 4; ++g) {
      if (lkq < 2) {
        int brow = g * H_ + j0 + wc * 16 + lcol;
        bf[g] = *(const f16x8*)(Wih0 + (size_t)brow * 16 + lkq * 8);
      } else bf[g] = za;
    }
#pragma unroll
    for (int m = 0; m < 4; ++m)
#pragma unroll
      for (int g = 0; g < 4; ++g)
        acc[m][g] = __builtin_amdgcn_mfma_f32_16x16x32_f16(af[m], bf[g], acc[m][g], 0, 0, 0);
    lstm_epi_g(acc, nullptr, nullptr, h0out, b0, jcol, wr, lkq, 0, 0);
  }
}

// ---------------------------------------------------------------------------
// obs-phase projection heads (unchanged)
// ---------------------------------------------------------------------------
template<int MODE>
__global__ __launch_bounds__(256)
void proj_update(const f16* __restrict__ h1, const float* __restrict__ Wl,
                 const float* __restrict__ bl, const float* __restrict__ sv,
                 float* __restrict__ v_buf, float* __restrict__ x_buf,
                 float* __restrict__ out_t, f16* __restrict__ a16)
{
  __shared__ f16 lh[16 * 1024];
  const int b0r = blockIdx.x * 16;
  const int tid = threadIdx.x;
#pragma unroll
  for (int c = 0; c < 8; ++c) {
    int o = c * 256 + tid;
    *(f16x8*)&lh[o * 8] = *(const f16x8*)&h1[(size_t)b0r * 1024 + o * 8];
  }
  __syncthreads();
  const int br = tid >> 4;
  const int f  = tid & 15;
  float s0 = 0, s1 = 0, s2 = 0, s3 = 0;
  const float4* wp = (const float4*)(Wl + (size_t)f * 1024);
#pragma unroll 4
  for (int k8 = 0; k8 < 128; ++k8) {
    f16x8 hv = *(const f16x8*)&lh[br * 1024 + k8 * 8];
    float4 w0 = wp[k8 * 2], w1 = wp[k8 * 2 + 1];
    s0 += (float)hv[0] * w0.x + (float)hv[4] * w1.x;
    s1 += (float)hv[1] * w0.y + (float)hv[5] * w1.y;
    s2 += (float)hv[2] * w0.z + (float)hv[6] * w1.z;
    s3 += (float)hv[3] * w0.w + (float)hv[7] * w1.w;
  }
  float t = fast_tanh(bl[f] + ((s0 + s1) + (s2 + s3)));
  int idx = (b0r + br) * F_ + f;
  if (MODE == 0) {
    v_buf[idx] = sv[0] * t;
  } else {
    float v = v_buf[idx] + sv[0] * t;
    v_buf[idx] = v;
    float x = x_buf[idx] + v;
    x_buf[idx] = x;
    out_t[idx] = x;
    a16[idx] = (f16)t;
  }
}

// ---------------------------------------------------------------------------
// input prep (merged m16 [t][4096][16]: rows 0-2047 v_seq, 2048+ a_seq)
// ---------------------------------------------------------------------------
__global__ void prep_kernel(const float* __restrict__ x_in, const float* __restrict__ y,
                            const float* __restrict__ v_in, const float* __restrict__ sx,
                            float* __restrict__ out, float* __restrict__ x_buf,
                            f16* __restrict__ m16)
{
  const float s = sx[0];
  int gid = blockIdx.x * blockDim.x + threadIdx.x;
  int gs  = gridDim.x * blockDim.x;
  for (int i = gid; i < B_ * OBS_ * F_; i += gs) {
    int b = i / (OBS_ * F_);
    int rem = i - b * (OBS_ * F_);
    int t = rem >> 4;
    int f = rem & 15;
    float v = v_in[i];
    m16[((size_t)t * 4096 + b) * F_ + f] = (f16)v;
    if (t < OBS_ - 1)
      m16[((size_t)t * 4096 + 2048 + b) * F_ + f] = (f16)(v_in[i + F_] - v);
  }
  for (int i = gid; i < PRED_ * B_ * F_; i += gs) {
    int t = i / (B_ * F_);
    int rem = i - t * (B_ * F_);
    int b = rem >> 4;
    int f = rem & 15;
    out[PRED_ * B_ * F_ + i] = s * y[(b * PRED_ + t) * F_ + f];
  }
  for (int i = gid; i < B_ * F_; i += gs) {
    int b = i >> 4;
    int f = i & 15;
    x_buf[i] = s * x_in[(b * OBS_ + (OBS_ - 1)) * F_ + f];
  }
}

// ---------------------------------------------------------------------------
// weight conversion fp32 -> f16 + bias sums
// ---------------------------------------------------------------------------
struct ConvArgs {
  const float* src[8];
  f16*         dst[8];
  int          n[8];
  const float* b1[4];
  const float* b2[4];
  float*       bd[4];
};

__global__ void convw(ConvArgs a)
{
  int gid = blockIdx.x * blockDim.x + threadIdx.x;
  int gs  = gridDim.x * blockDim.x;
#pragma unroll
  for (int s = 0; s < 8; ++s) {
    int n4 = a.n[s] >> 2;
    for (int i = gid; i < n4; i += gs) {
      float4 v = ((const float4*)a.src[s])[i];
      f16x4 d = {(f16)v.x, (f16)v.y, (f16)v.z, (f16)v.w};
      ((f16x4*)a.dst[s])[i] = d;
    }
  }
#pragma unroll
  for (int s = 0; s < 4; ++s) {
    for (int i = gid; i < GN_; i += gs) a.bd[s][i] = a.b1[s][i] + a.b2[s][i];
  }
}

// ---------------------------------------------------------------------------
extern "C" void kernel_launch(void* const* d_in, const int* in_sizes, int n_in,
                              void* d_out, int out_size, void* d_ws, size_t ws_size,
                              hipStream_t stream)
{
  (void)in_sizes; (void)n_in; (void)out_size; (void)ws_size;

  const float* x_in  = (const float*)d_in[0];
  const float* y     = (const float*)d_in[1];
  const float* v_in  = (const float*)d_in[2];
  const float* sx    = (const float*)d_in[3];
  const float* sv    = (const float*)d_in[4];
  const float* vWih0 = (const float*)d_in[5];
  const float* vWhh0 = (const float*)d_in[6];
  const float* vbih0 = (const float*)d_in[7];
  const float* vbhh0 = (const float*)d_in[8];
  const float* vWih1 = (const float*)d_in[9];
  const float* vWhh1 = (const float*)d_in[10];
  const float* vbih1 = (const float*)d_in[11];
  const float* vbhh1 = (const float*)d_in[12];
  const float* vWl   = (const float*)d_in[13];
  const float* vbl   = (const float*)d_in[14];
  const float* aWih0 = (const float*)d_in[15];
  const float* aWhh0 = (const float*)d_in[16];
  const float* abih0 = (const float*)d_in[17];
  const float* abhh0 = (const float*)d_in[18];
  const float* aWih1 = (const float*)d_in[19];
  const float* aWhh1 = (const float*)d_in[20];
  const float* abih1 = (const float*)d_in[21];
  const float* abhh1 = (const float*)d_in[22];
  const float* aWl   = (const float*)d_in[23];
  const float* abl   = (const float*)d_in[24];
  float* out = (float*)d_out;

  char* ws = (char*)d_ws;
  size_t off = 0;
  auto alloc = [&](size_t bytes) {
    char* p = ws + off;
    off += (bytes + 255) & ~(size_t)255;
    return p;
  };
  f16* vWih0f = (f16*)alloc((size_t)GN_ * F_ * 2);
  f16* vWhh0f = (f16*)alloc((size_t)GN_ * H_ * 2);
  f16* vWih1f = (f16*)alloc((size_t)GN_ * H_ * 2);
  f16* vWhh1f = (f16*)alloc((size_t)GN_ * H_ * 2);
  f16* aWih0f = (f16*)alloc((size_t)GN_ * F_ * 2);
  f16* aWhh0f = (f16*)alloc((size_t)GN_ * H_ * 2);
  f16* aWih1f = (f16*)alloc((size_t)GN_ * H_ * 2);
  f16* aWhh1f = (f16*)alloc((size_t)GN_ * H_ * 2);
  float* vb0 = (float*)alloc(GN_ * 4);
  float* vb1 = (float*)alloc(GN_ * 4);
  float* ab0 = (float*)alloc(GN_ * 4);
  float* ab1 = (float*)alloc(GN_ * 4);
  f16* m16 = (f16*)alloc((size_t)OBS_ * 4096 * F_ * 2);
  f16* h0a = (f16*)alloc((size_t)4096 * H_ * 2);
  f16* h0b = (f16*)alloc((size_t)4096 * H_ * 2);
  f16* h1a = (f16*)alloc((size_t)4096 * H_ * 2);
  f16* h1b = (f16*)alloc((size_t)4096 * H_ * 2);
  float* c0 = (float*)alloc((size_t)4096 * H_ * 4);
  float* c1 = (float*)alloc((size_t)4096 * H_ * 4);
  f16* a16   = (f16*)alloc((size_t)B_ * F_ * 2);
  float* v_buf = (float*)alloc((size_t)B_ * F_ * 4);
  float* x_buf = (float*)alloc((size_t)B_ * F_ * 4);
  float* ppart = (float*)alloc((size_t)B_ * 16 * F_ * 4);   // [2048][16][16]

  ConvArgs ca;
  ca.src[0] = vWih0; ca.dst[0] = vWih0f; ca.n[0] = GN_ * F_;
  ca.src[1] = vWhh0; ca.dst[1] = vWhh0f; ca.n[1] = GN_ * H_;
  ca.src[2] = vWih1; ca.dst[2] = vWih1f; ca.n[2] = GN_ * H_;
  ca.src[3] = vWhh1; ca.dst[3] = vWhh1f; ca.n[3] = GN_ * H_;
  ca.src[4] = aWih0; ca.dst[4] = aWih0f; ca.n[4] = GN_ * F_;
  ca.src[5] = aWhh0; ca.dst[5] = aWhh0f; ca.n[5] = GN_ * H_;
  ca.src[6] = aWih1; ca.dst[6] = aWih1f; ca.n[6] = GN_ * H_;
  ca.src[7] = aWhh1; ca.dst[7] = aWhh1f; ca.n[7] = GN_ * H_;
  ca.b1[0] = vbih0; ca.b2[0] = vbhh0; ca.bd[0] = vb0;
  ca.b1[1] = vbih1; ca.b2[1] = vbhh1; ca.bd[1] = vb1;
  ca.b1[2] = abih0; ca.b2[2] = abhh0; ca.bd[2] = ab0;
  ca.b1[3] = abih1; ca.b2[3] = abhh1; ca.bd[3] = ab1;
  convw<<<1024, 256, 0, stream>>>(ca);
  prep_kernel<<<1024, 256, 0, stream>>>(x_in, y, v_in, sx, out, x_buf, m16);

  auto h0buf = [&](int t) { return (t & 1) ? h0b : h0a; };
  auto h1buf = [&](int t) { return (t & 1) ? h1b : h1a; };
  StepArgs dummy{};

  // ---- obs t=0: layer0 only (512 blocks, M=4096) ----
  {
    StepArgs q{};
    q.A16 = m16; q.W16v = vWih0f; q.W16a = aWih0f;
    q.bv = vb0; q.ba = ab0;
    q.cout = c0; q.hout = h0buf(0);
    q.k16 = 1; q.nt = 0; q.hasc = 0; q.writec = 1;
    obs_pair<<<512, 512, 0, stream>>>(dummy, q, 0);
  }

  // ---- obs pairs: {layer1(t-1) first (LPT) || layer0(t)} for t=1..19 ----
  for (int t = 1; t < OBS_; ++t) {
    int u = t - 1;
    StepArgs q{};
    q.A16 = m16 + (size_t)t * 4096 * F_;
    q.W16v = vWih0f; q.W16a = aWih0f;
    q.A0 = h0buf(t - 1); q.W0v = vWhh0f; q.W0a = aWhh0f;
    q.bv = vb0; q.ba = ab0;
    q.cin = c0; q.cout = c0; q.hout = h0buf(t);
    q.k16 = 1; q.nt = 32; q.hasc = 1; q.writec = 1;

    StepArgs r{};
    r.A0 = h0buf(u); r.W0v = vWih1f; r.W0a = aWih1f;
    r.A1 = (u > 0) ? h1buf(u - 1) : nullptr;
    r.W1v = vWhh1f; r.W1a = aWhh1f;
    r.bv = vb1; r.ba = ab1;
    r.cin = c1; r.cout = c1; r.hout = h1buf(u);
    r.k16 = 0; r.nt = (u > 0) ? 64 : 32; r.hasc = (u > 0); r.writec = 1;

    // layer1 (long) blocks first; layer0 v-only at t=19 (M=2048 -> 256 blocks)
    int qblocks = (t == OBS_ - 1) ? 256 : 512;
    obs_pair<<<512 + qblocks, 512, 0, stream>>>(r, q, 512);
  }

  // ---- obs final: layer1(19), v rows only (M=2048 -> 256 blocks) ----
  {
    StepArgs r{};
    r.A0 = h0buf(19); r.W0v = vWih1f; r.W0a = aWih1f;
    r.A1 = h1buf(18); r.W1v = vWhh1f; r.W1a = aWhh1f;
    r.bv = vb1; r.ba = ab1;
    r.cin = c1; r.cout = c1; r.hout = h1buf(19);
    r.k16 = 0; r.nt = 64; r.hasc = 1; r.writec = 1;
    obs_pair<<<256, 512, 0, stream>>>(r, dummy, 256);
  }

  // heads: v from h1(19); a from h1(18) rows 2048+
  proj_update<0><<<128, 256, 0, stream>>>(h1buf(19), vWl, vbl, sv,
                                          v_buf, nullptr, nullptr, nullptr);
  proj_update<1><<<128, 256, 0, stream>>>(h1buf(18) + (size_t)2048 * H_, aWl, abl, sv,
                                          v_buf, x_buf, out, a16);

  // ---- autoregressive scan: 2 launches/step ----
  scan_l0<1, 0><<<512, 256, 0, stream>>>(ppart, a16, abl, sv, v_buf, x_buf, out,
                                         ab0, aWih0f, h0a);
  scan_l1<<<256, 512, 0, stream>>>(h0a, aWih1f, ab1, aWl, ppart);
  for (int t = 2; t < PRED_; ++t) {
    scan_l0<0, 0><<<512, 256, 0, stream>>>(ppart, nullptr, abl, sv, v_buf, x_buf,
                                           out + (size_t)(t - 1) * B_ * F_,
                                           ab0, aWih0f, h0a);
    scan_l1<<<256, 512, 0, stream>>>(h0a, aWih1f, ab1, aWl, ppart);
  }
  scan_l0<0, 1><<<16, 256, 0, stream>>>(ppart, nullptr, abl, sv, v_buf, x_buf,
                                        out + (size_t)(PRED_ - 1) * B_ * F_,
                                        ab0, aWih0f, h0a);
}